// Round 1
// baseline (559.113 us; speedup 1.0000x reference)
//
#include <hip/hip_runtime.h>

// OctreeDWConvBn: out[n,c] = BN_c( sum_k data[neigh[n,k],c] * weight[k,c] )
// fp32 everywhere. N=131072, C=192, K=27.

static constexpr int NN = 131072;   // nodes
static constexpr int CC = 192;      // channels
static constexpr int KK = 27;       // stencil taps
static constexpr int NB = 32;       // nodes per block (serial)
static constexpr float BN_EPS = 1e-5f;

// ---------------------------------------------------------------------------
// Kernel 1: depthwise conv + per-block partial BN sums.
// Block = 192 threads (1 thread = 1 channel, 3 waves). Each block handles NB
// consecutive nodes. Neighbor indices are block-uniform -> scalar loads.
// Each wave's gather read is 256 B contiguous within a data row (coalesced).
// ---------------------------------------------------------------------------
__global__ __launch_bounds__(CC) void conv_bn_partial(
    const float* __restrict__ data,
    const int*   __restrict__ neigh,
    const float* __restrict__ weight,
    float*       __restrict__ conv_out,   // [NN, CC] (d_out, pre-normalize)
    float*       __restrict__ ch_sum,     // [CC]
    float*       __restrict__ ch_sumsq)   // [CC]
{
    const int c    = threadIdx.x;
    const int base = blockIdx.x * NB;

    // Depthwise weights for this channel: 27 registers, loaded once.
    float w[KK];
#pragma unroll
    for (int k = 0; k < KK; ++k) w[k] = weight[k * CC + c];

    float s = 0.f, ss = 0.f;

    for (int n = 0; n < NB; ++n) {
        const int node = base + n;                  // block-uniform
        const int* nrow = neigh + node * KK;        // block-uniform base
        float acc = 0.f;
#pragma unroll
        for (int k = 0; k < KK; ++k) {
            const int idx = nrow[k];                // uniform -> s_load
            acc = fmaf(data[idx * CC + c], w[k], acc);
        }
        conv_out[node * CC + c] = acc;
        s  += acc;
        ss += acc * acc;
    }

    // One atomic per channel per block: 4096 atomics/address total.
    atomicAdd(&ch_sum[c],   s);
    atomicAdd(&ch_sumsq[c], ss);
}

// ---------------------------------------------------------------------------
// Kernel 2: fold channel sums into affine scale/bias. 1 block x 192 threads.
// ---------------------------------------------------------------------------
__global__ __launch_bounds__(CC) void bn_finalize(
    const float* __restrict__ ch_sum,
    const float* __restrict__ ch_sumsq,
    const float* __restrict__ gamma,
    const float* __restrict__ beta,
    float*       __restrict__ scale,
    float*       __restrict__ bias)
{
    const int c = threadIdx.x;
    const float inv_n = 1.0f / (float)NN;
    const float m  = ch_sum[c] * inv_n;
    const float v  = ch_sumsq[c] * inv_n - m * m;
    const float sc = gamma[c] * rsqrtf(v + BN_EPS);
    scale[c] = sc;
    bias[c]  = beta[c] - m * sc;
}

// ---------------------------------------------------------------------------
// Kernel 3: in-place normalize of d_out, float4 vectorized.
// NN*CC/4 = 6291456 float4 elements; 48 float4 per row.
// ---------------------------------------------------------------------------
__global__ __launch_bounds__(256) void bn_apply(
    float* __restrict__ out,
    const float* __restrict__ scale,
    const float* __restrict__ bias)
{
    const int i = blockIdx.x * 256 + threadIdx.x;   // float4 index
    const int cb = (i % (CC / 4)) * 4;              // channel base of this float4

    float4 v  = reinterpret_cast<float4*>(out)[i];
    const float4 sc = *reinterpret_cast<const float4*>(scale + cb);
    const float4 bi = *reinterpret_cast<const float4*>(bias + cb);
    v.x = fmaf(v.x, sc.x, bi.x);
    v.y = fmaf(v.y, sc.y, bi.y);
    v.z = fmaf(v.z, sc.z, bi.z);
    v.w = fmaf(v.w, sc.w, bi.w);
    reinterpret_cast<float4*>(out)[i] = v;
}

extern "C" void kernel_launch(void* const* d_in, const int* in_sizes, int n_in,
                              void* d_out, int out_size, void* d_ws, size_t ws_size,
                              hipStream_t stream) {
    const float* data   = (const float*)d_in[0];   // [NN, CC]
    const int*   neigh  = (const int*)  d_in[1];   // [NN, KK]
    const float* weight = (const float*)d_in[2];   // [KK, CC]
    const float* gamma  = (const float*)d_in[3];   // [CC]
    const float* beta   = (const float*)d_in[4];   // [CC]
    float* out = (float*)d_out;                    // [NN, CC]

    // Workspace layout (floats): sum[192] | sumsq[192] | scale[192] | bias[192]
    float* ch_sum   = (float*)d_ws;
    float* ch_sumsq = ch_sum + CC;
    float* scale    = ch_sumsq + CC;
    float* bias     = scale + CC;

    // Zero the atomic accumulators (ws is re-poisoned to 0xAA every call).
    hipMemsetAsync(ch_sum, 0, 2 * CC * sizeof(float), stream);

    conv_bn_partial<<<NN / NB, CC, 0, stream>>>(data, neigh, weight, out,
                                                ch_sum, ch_sumsq);
    bn_finalize<<<1, CC, 0, stream>>>(ch_sum, ch_sumsq, gamma, beta, scale, bias);
    bn_apply<<<(NN * CC / 4) / 256, 256, 0, stream>>>(out, scale, bias);
}

// Round 2
// 420.963 us; speedup vs baseline: 1.3282x; 1.3282x over previous
//
#include <hip/hip_runtime.h>

// OctreeDWConvBn: out[n,c] = BN_c( sum_k data[neigh[n,k],c] * weight[k,c] )
// N=131072, C=192, K=27. fp32 in/out; gathered operand staged as bf16.

static constexpr int NN = 131072;   // nodes
static constexpr int CC = 192;      // channels
static constexpr int KK = 27;       // stencil taps
static constexpr int NB = 32;       // nodes per block (serial)
static constexpr float BN_EPS = 1e-5f;

// ---------------------------------------------------------------------------
// Kernel 0: fp32 -> bf16 (RNE) staging of `data`. Read float4, write ushort4.
// 150 MB streamed; ~25 us.
// ---------------------------------------------------------------------------
__device__ __forceinline__ unsigned short f2bf_rne(float x) {
    unsigned u = __float_as_uint(x);
    return (unsigned short)((u + 0x7FFFu + ((u >> 16) & 1u)) >> 16);
}

__global__ __launch_bounds__(256) void cvt_bf16(
    const float* __restrict__ src,
    unsigned short* __restrict__ dst)
{
    const int i = blockIdx.x * 256 + threadIdx.x;     // float4 index
    const float4 v = reinterpret_cast<const float4*>(src)[i];
    ushort4 o;
    o.x = f2bf_rne(v.x);
    o.y = f2bf_rne(v.y);
    o.z = f2bf_rne(v.z);
    o.w = f2bf_rne(v.w);
    reinterpret_cast<ushort4*>(dst)[i] = o;
}

// ---------------------------------------------------------------------------
// Kernel 1 (bf16 path): depthwise conv + per-block partial BN sums.
// Block = 192 threads (1 thread = 1 channel). Neighbor indices block-uniform
// -> scalar loads. Gathered rows are bf16: 2 B/lane, 384 B/row (halved).
// ---------------------------------------------------------------------------
__global__ __launch_bounds__(CC) void conv_bn_partial_bf16(
    const unsigned short* __restrict__ data_bf,  // [NN, CC] bf16 bits
    const int*   __restrict__ neigh,
    const float* __restrict__ weight,
    float*       __restrict__ conv_out,          // [NN, CC]
    float*       __restrict__ ch_sum,            // [CC]
    float*       __restrict__ ch_sumsq)          // [CC]
{
    const int c    = threadIdx.x;
    const int base = blockIdx.x * NB;

    float w[KK];
#pragma unroll
    for (int k = 0; k < KK; ++k) w[k] = weight[k * CC + c];

    float s = 0.f, ss = 0.f;

    for (int n = 0; n < NB; ++n) {
        const int node = base + n;                  // block-uniform
        const int* nrow = neigh + node * KK;        // uniform -> s_load
        float acc = 0.f;
#pragma unroll
        for (int k = 0; k < KK; ++k) {
            const int idx = nrow[k];
            const float v = __uint_as_float(
                (unsigned)data_bf[idx * CC + c] << 16);
            acc = fmaf(v, w[k], acc);
        }
        conv_out[node * CC + c] = acc;
        s  += acc;
        ss += acc * acc;
    }

    atomicAdd(&ch_sum[c],   s);
    atomicAdd(&ch_sumsq[c], ss);
}

// ---------------------------------------------------------------------------
// Kernel 1 (fallback fp32 path, used only if ws can't hold the bf16 stage).
// ---------------------------------------------------------------------------
__global__ __launch_bounds__(CC) void conv_bn_partial_f32(
    const float* __restrict__ data,
    const int*   __restrict__ neigh,
    const float* __restrict__ weight,
    float*       __restrict__ conv_out,
    float*       __restrict__ ch_sum,
    float*       __restrict__ ch_sumsq)
{
    const int c    = threadIdx.x;
    const int base = blockIdx.x * NB;

    float w[KK];
#pragma unroll
    for (int k = 0; k < KK; ++k) w[k] = weight[k * CC + c];

    float s = 0.f, ss = 0.f;

    for (int n = 0; n < NB; ++n) {
        const int node = base + n;
        const int* nrow = neigh + node * KK;
        float acc = 0.f;
#pragma unroll
        for (int k = 0; k < KK; ++k) {
            acc = fmaf(data[nrow[k] * CC + c], w[k], acc);
        }
        conv_out[node * CC + c] = acc;
        s  += acc;
        ss += acc * acc;
    }

    atomicAdd(&ch_sum[c],   s);
    atomicAdd(&ch_sumsq[c], ss);
}

// ---------------------------------------------------------------------------
// Kernel 2: fold channel sums into affine scale/bias. 1 block x 192 threads.
// ---------------------------------------------------------------------------
__global__ __launch_bounds__(CC) void bn_finalize(
    const float* __restrict__ ch_sum,
    const float* __restrict__ ch_sumsq,
    const float* __restrict__ gamma,
    const float* __restrict__ beta,
    float*       __restrict__ scale,
    float*       __restrict__ bias)
{
    const int c = threadIdx.x;
    const float inv_n = 1.0f / (float)NN;
    const float m  = ch_sum[c] * inv_n;
    const float v  = ch_sumsq[c] * inv_n - m * m;
    const float sc = gamma[c] * rsqrtf(v + BN_EPS);
    scale[c] = sc;
    bias[c]  = beta[c] - m * sc;
}

// ---------------------------------------------------------------------------
// Kernel 3: in-place normalize of d_out, float4 vectorized.
// ---------------------------------------------------------------------------
__global__ __launch_bounds__(256) void bn_apply(
    float* __restrict__ out,
    const float* __restrict__ scale,
    const float* __restrict__ bias)
{
    const int i = blockIdx.x * 256 + threadIdx.x;   // float4 index
    const int cb = (i % (CC / 4)) * 4;              // channel base

    float4 v  = reinterpret_cast<float4*>(out)[i];
    const float4 sc = *reinterpret_cast<const float4*>(scale + cb);
    const float4 bi = *reinterpret_cast<const float4*>(bias + cb);
    v.x = fmaf(v.x, sc.x, bi.x);
    v.y = fmaf(v.y, sc.y, bi.y);
    v.z = fmaf(v.z, sc.z, bi.z);
    v.w = fmaf(v.w, sc.w, bi.w);
    reinterpret_cast<float4*>(out)[i] = v;
}

extern "C" void kernel_launch(void* const* d_in, const int* in_sizes, int n_in,
                              void* d_out, int out_size, void* d_ws, size_t ws_size,
                              hipStream_t stream) {
    const float* data   = (const float*)d_in[0];   // [NN, CC]
    const int*   neigh  = (const int*)  d_in[1];   // [NN, KK]
    const float* weight = (const float*)d_in[2];   // [KK, CC]
    const float* gamma  = (const float*)d_in[3];   // [CC]
    const float* beta   = (const float*)d_in[4];   // [CC]
    float* out = (float*)d_out;                    // [NN, CC]

    // Workspace: stats (4*CC floats, padded to 4096 B) | bf16 staged data.
    float* ch_sum   = (float*)d_ws;
    float* ch_sumsq = ch_sum + CC;
    float* scale    = ch_sumsq + CC;
    float* bias     = scale + CC;
    unsigned short* data_bf =
        (unsigned short*)((char*)d_ws + 4096);
    const size_t need = 4096 + (size_t)NN * CC * sizeof(unsigned short);

    hipMemsetAsync(ch_sum, 0, 2 * CC * sizeof(float), stream);

    if (ws_size >= need) {
        cvt_bf16<<<(NN * CC / 4) / 256, 256, 0, stream>>>(data, data_bf);
        conv_bn_partial_bf16<<<NN / NB, CC, 0, stream>>>(
            data_bf, neigh, weight, out, ch_sum, ch_sumsq);
    } else {
        conv_bn_partial_f32<<<NN / NB, CC, 0, stream>>>(
            data, neigh, weight, out, ch_sum, ch_sumsq);
    }
    bn_finalize<<<1, CC, 0, stream>>>(ch_sum, ch_sumsq, gamma, beta, scale, bias);
    bn_apply<<<(NN * CC / 4) / 256, 256, 0, stream>>>(out, scale, bias);
}